// Round 9
// baseline (6401.791 us; speedup 1.0000x reference)
//
#include <hip/hip_runtime.h>
#include <stdint.h>

// Echo-state network — fp32 inputs, FLOAT32 outputs (logits fp32, preds int-like).
// Root cause of rounds 4-8: outputs were being written as bf16 u16 while the
// harness decodes d_out as float32 (reference returns fp32 logits / int32 preds).
// This round: identical verified fp32 VALU engine, outputs written as fp32.
// Recurrence: S_new[b][n][i] = tanh( sum_j W_res[b][i][j]*s[b][n][j]
//                                  + sum_v W_in[b][i][v]*X[n][t][v] )
// Head: fp32 dot + argmax (first-index ties).
// d_ws: two fp32 state ping-pong buffers, 12.6 MB (proven-safe size).

#define N_TOT 256
#define T_TOT 70
#define V_TOT 64
#define B_TOT 6
#define H_TOT 1024
#define C_TOT 4
#define F_TOT (B_TOT * H_TOT)
#define LDT 68  // LDS row stride in floats for [j][*] tiles

// ---------------------------------------------------------------------------
// Step kernel: 64x64 output tile per 256-thread WG. grid = 6*4*16 = 384.
// Thread (ty,tx) owns rows 4*ty..+3 (batch n) x cols 4*tx..+3 (unit i).
// ---------------------------------------------------------------------------
__global__ __launch_bounds__(256)
void esn_step_fp32(const float* __restrict__ X,      // [N,T,V]
                   const float* __restrict__ W_res,  // [B,H,H]
                   const float* __restrict__ W_in,   // [B,H,V]
                   const float* __restrict__ sprev,  // [B,N,H]
                   float* __restrict__ snext,        // [B,N,H]
                   int t, int first)
{
    __shared__ float sT[64 * LDT];  // [j][n]
    __shared__ float wT[64 * LDT];  // [j][i]

    const int id = blockIdx.x;
    const int b  = id >> 6;          // reservoir block 0..5
    const int mt = (id >> 4) & 3;    // batch tile 0..3
    const int it = id & 15;          // unit tile 0..15

    const int tid = threadIdx.x;
    const int ty  = tid >> 4;        // 0..15
    const int tx  = tid & 15;        // 0..15
    const int c4  = tx << 2;         // staging col group 0,4,...,60

    const int n0 = mt * 64;
    const int i0 = it * 64;

    float acc[4][4];
#pragma unroll
    for (int a = 0; a < 4; ++a)
#pragma unroll
        for (int c = 0; c < 4; ++c) acc[a][c] = 0.0f;

    if (!first) {
        const float* Ag = sprev + (size_t)(b * N_TOT + n0) * H_TOT;
        const float* Bg = W_res + (size_t)(b * H_TOT + i0) * H_TOT;
        for (int kc = 0; kc < 16; ++kc) {
            const int j0 = kc * 64;
            __syncthreads();  // previous iteration's LDS reads done
#pragma unroll
            for (int pp = 0; pp < 4; ++pp) {
                const int rr = ty + pp * 16;  // tile row 0..63
                const float4 av = *(const float4*)&Ag[(size_t)rr * H_TOT + j0 + c4];
                const float4 bv = *(const float4*)&Bg[(size_t)rr * H_TOT + j0 + c4];
                sT[(c4 + 0) * LDT + rr] = av.x;
                sT[(c4 + 1) * LDT + rr] = av.y;
                sT[(c4 + 2) * LDT + rr] = av.z;
                sT[(c4 + 3) * LDT + rr] = av.w;
                wT[(c4 + 0) * LDT + rr] = bv.x;
                wT[(c4 + 1) * LDT + rr] = bv.y;
                wT[(c4 + 2) * LDT + rr] = bv.z;
                wT[(c4 + 3) * LDT + rr] = bv.w;
            }
            __syncthreads();
#pragma unroll 4
            for (int j = 0; j < 64; ++j) {
                const float4 a = *(const float4*)&sT[j * LDT + 4 * ty];
                const float4 w = *(const float4*)&wT[j * LDT + 4 * tx];
                acc[0][0] += a.x * w.x; acc[0][1] += a.x * w.y;
                acc[0][2] += a.x * w.z; acc[0][3] += a.x * w.w;
                acc[1][0] += a.y * w.x; acc[1][1] += a.y * w.y;
                acc[1][2] += a.y * w.z; acc[1][3] += a.y * w.w;
                acc[2][0] += a.z * w.x; acc[2][1] += a.z * w.y;
                acc[2][2] += a.z * w.z; acc[2][3] += a.z * w.w;
                acc[3][0] += a.w * w.x; acc[3][1] += a.w * w.y;
                acc[3][2] += a.w * w.z; acc[3][3] += a.w * w.w;
            }
        }
    }

    // ---- input term: += X_t * W_in[b]^T  (single K-chunk of 64) ----
    __syncthreads();
    {
#pragma unroll
        for (int pp = 0; pp < 4; ++pp) {
            const int rr = ty + pp * 16;
            const float4 av =
                *(const float4*)&X[((size_t)(n0 + rr) * T_TOT + t) * V_TOT + c4];
            const float4 bv =
                *(const float4*)&W_in[(size_t)(b * H_TOT + i0 + rr) * V_TOT + c4];
            sT[(c4 + 0) * LDT + rr] = av.x;
            sT[(c4 + 1) * LDT + rr] = av.y;
            sT[(c4 + 2) * LDT + rr] = av.z;
            sT[(c4 + 3) * LDT + rr] = av.w;
            wT[(c4 + 0) * LDT + rr] = bv.x;
            wT[(c4 + 1) * LDT + rr] = bv.y;
            wT[(c4 + 2) * LDT + rr] = bv.z;
            wT[(c4 + 3) * LDT + rr] = bv.w;
        }
        __syncthreads();
#pragma unroll 4
        for (int j = 0; j < 64; ++j) {
            const float4 a = *(const float4*)&sT[j * LDT + 4 * ty];
            const float4 w = *(const float4*)&wT[j * LDT + 4 * tx];
            acc[0][0] += a.x * w.x; acc[0][1] += a.x * w.y;
            acc[0][2] += a.x * w.z; acc[0][3] += a.x * w.w;
            acc[1][0] += a.y * w.x; acc[1][1] += a.y * w.y;
            acc[1][2] += a.y * w.z; acc[1][3] += a.y * w.w;
            acc[2][0] += a.z * w.x; acc[2][1] += a.z * w.y;
            acc[2][2] += a.z * w.z; acc[2][3] += a.z * w.w;
            acc[3][0] += a.w * w.x; acc[3][1] += a.w * w.y;
            acc[3][2] += a.w * w.z; acc[3][3] += a.w * w.w;
        }
    }

    // ---- epilogue: tanh + store fp32 state ----
    float* outp = snext + (size_t)(b * N_TOT + n0) * H_TOT + i0;
#pragma unroll
    for (int mm = 0; mm < 4; ++mm) {
        float4 o;
        o.x = tanhf(acc[mm][0]);
        o.y = tanhf(acc[mm][1]);
        o.z = tanhf(acc[mm][2]);
        o.w = tanhf(acc[mm][3]);
        *(float4*)&outp[(size_t)(4 * ty + mm) * H_TOT + 4 * tx] = o;
    }
}

// ---------------------------------------------------------------------------
// Head for step t (pure fp32): logits[t][n][c] = s[n][:] . W_lin[t][c][:] + b
// preds[t][n] = argmax_c (first-index tie-break). One WG per n.
// OUTPUTS WRITTEN AS FP32.
// ---------------------------------------------------------------------------
__global__ __launch_bounds__(256)
void esn_head_fp32(const float* __restrict__ s,      // [B,N,H] (this step)
                   const float* __restrict__ W_lin,  // [T,C,F]
                   const float* __restrict__ b_lin,  // [T,C]
                   float* __restrict__ logits,       // [T,N,C] fp32
                   float* __restrict__ preds,        // [T,N]   fp32 (0..3)
                   int t)
{
    const int n   = blockIdx.x;
    const int tid = threadIdx.x;

    float acc[4] = {0.f, 0.f, 0.f, 0.f};
    const float* wl = W_lin + (size_t)t * C_TOT * F_TOT;

#pragma unroll
    for (int p = 0; p < 3; ++p) {
        const int f    = p * 2048 + tid * 8;
        const int bblk = f >> 10;
        const int off  = f & 1023;
        const float* sp = &s[(size_t)(bblk * N_TOT + n) * H_TOT + off];
        const float4 f0 = *(const float4*)&sp[0];
        const float4 f1 = *(const float4*)&sp[4];
        const float feat[8] = {f0.x, f0.y, f0.z, f0.w, f1.x, f1.y, f1.z, f1.w};
#pragma unroll
        for (int c = 0; c < 4; ++c) {
            const float4 w0 = *(const float4*)&wl[(size_t)c * F_TOT + f];
            const float4 w1 = *(const float4*)&wl[(size_t)c * F_TOT + f + 4];
            acc[c] += feat[0] * w0.x + feat[1] * w0.y + feat[2] * w0.z +
                      feat[3] * w0.w + feat[4] * w1.x + feat[5] * w1.y +
                      feat[6] * w1.z + feat[7] * w1.w;
        }
    }

#pragma unroll
    for (int off = 32; off > 0; off >>= 1) {
#pragma unroll
        for (int c = 0; c < 4; ++c)
            acc[c] += __shfl_down(acc[c], off);
    }

    __shared__ float red[4][4];
    const int wave = tid >> 6;
    if ((tid & 63) == 0) {
#pragma unroll
        for (int c = 0; c < 4; ++c) red[wave][c] = acc[c];
    }
    __syncthreads();
    if (tid == 0) {
        float l[4];
#pragma unroll
        for (int c = 0; c < 4; ++c)
            l[c] = red[0][c] + red[1][c] + red[2][c] + red[3][c] +
                   b_lin[t * C_TOT + c];
        const size_t obase = (size_t)(t * N_TOT + n) * C_TOT;
#pragma unroll
        for (int c = 0; c < 4; ++c) logits[obase + c] = l[c];
        int arg = 0;
        float best = l[0];
#pragma unroll
        for (int c = 1; c < 4; ++c)
            if (l[c] > best) { best = l[c]; arg = c; }
        preds[(size_t)t * N_TOT + n] = (float)arg;
    }
}

extern "C" void kernel_launch(void* const* d_in, const int* in_sizes, int n_in,
                              void* d_out, int out_size, void* d_ws, size_t ws_size,
                              hipStream_t stream) {
    // identify inputs by size (elements or bytes), robust to any permutation;
    // element/byte count sets have no cross-collisions.
    const long long szX    = (long long)N_TOT * T_TOT * V_TOT;
    const long long szWres = (long long)B_TOT * H_TOT * H_TOT;
    const long long szWin  = (long long)B_TOT * H_TOT * V_TOT;
    const long long szWlin = (long long)T_TOT * C_TOT * F_TOT;
    const long long szBlin = (long long)T_TOT * C_TOT;

    const float *X = 0, *W_res = 0, *W_in = 0, *W_lin = 0, *b_lin = 0;
    for (int i = 0; i < n_in; ++i) {
        const long long s = (long long)in_sizes[i];
        if      (s == szX    || s == 4 * szX)    X     = (const float*)d_in[i];
        else if (s == szWres || s == 4 * szWres) W_res = (const float*)d_in[i];
        else if (s == szWin  || s == 4 * szWin)  W_in  = (const float*)d_in[i];
        else if (s == szWlin || s == 4 * szWlin) W_lin = (const float*)d_in[i];
        else if (s == szBlin || s == 4 * szBlin) b_lin = (const float*)d_in[i];
    }
    if (!X || !W_res || !W_in || !W_lin || !b_lin) {
        X     = (const float*)d_in[0];
        W_res = (const float*)d_in[1];
        W_in  = (const float*)d_in[2];
        W_lin = (const float*)d_in[3];
        b_lin = (const float*)d_in[4];
    }

    float* out    = (float*)d_out;
    float* logits = out;                                  // T*N*C fp32
    float* preds  = out + (size_t)T_TOT * N_TOT * C_TOT;  // T*N   fp32

    // workspace: two fp32 state ping-pong buffers (6.29 MB each)
    const size_t nS = (size_t)B_TOT * N_TOT * H_TOT;
    float* sA = (float*)d_ws;
    float* sB = sA + nS;

    for (int t = 0; t < T_TOT; ++t) {
        const float* prev = (t & 1) ? sB : sA;
        float*       next = (t & 1) ? sA : sB;
        esn_step_fp32<<<B_TOT * 4 * 16, 256, 0, stream>>>(
            X, W_res, W_in, prev, next, t, t == 0 ? 1 : 0);
        esn_head_fp32<<<N_TOT, 256, 0, stream>>>(
            next, W_lin, b_lin, logits, preds, t);
    }
}

// Round 11
// 4409.995 us; speedup vs baseline: 1.4517x; 1.4517x over previous
//
#include <hip/hip_runtime.h>
#include <stdint.h>

// Echo-state network (fp32 in, fp32 out). Round 11: split-fp16 MFMA engine.
// R10 proved the f16 MFMA structure correct (logits passed) but single-fp16
// precision flips argmax preds (Output 1 err 2.0). This round keeps fp32-class
// numerics: every operand is split in-register into (hi, lo*4096) fp16 pairs
// at LDS staging (scaling keeps residuals in fp16 normal range; avoids MFMA
// subnormal-flush risk). 3 MFMAs per product: hi*hi -> acc, hi*lo + lo*hi ->
// accl; epilogue: acc + accl/4096. Dropped lo*lo ~ 2^-23 relative = fp32-class
// per-step noise -> trajectory deviation in R9's passing band.
// State stays fp32 in d_ws (12.6 MB proven-safe); head is R9's verbatim.

typedef _Float16 f16;
typedef _Float16 f16x8 __attribute__((ext_vector_type(8)));
typedef float floatx4 __attribute__((ext_vector_type(4)));

#define N_TOT 256
#define T_TOT 70
#define V_TOT 64
#define B_TOT 6
#define H_TOT 1024
#define C_TOT 4
#define F_TOT (B_TOT * H_TOT)
#define LDA 72          // f16 LDS row stride (144 B): <=2-way bank aliasing (free)
#define LO_SCALE 4096.0f
#define LO_INV   (1.0f / 4096.0f)

union U2H4 { f16 h[4]; uint2 v; };

// split one float4 into fp16 hi and scaled-lo quads
static __device__ __forceinline__ void split4(const float4 v, U2H4& hi, U2H4& lo)
{
    const float x[4] = {v.x, v.y, v.z, v.w};
#pragma unroll
    for (int j = 0; j < 4; ++j) {
        const f16 h = (f16)x[j];
        hi.h[j] = h;
        lo.h[j] = (f16)((x[j] - (float)h) * LO_SCALE);
    }
}

// ---------------------------------------------------------------------------
// Step: S_new[b][n][i] = tanh( sum_j W_res[b][i][j]*s[b][n][j]
//                            + sum_v W_in[b][i][v]*X[n][t][v] )
// 64x64 tile per 256-thread WG; grid = 6*4*16 = 384. Wave (wm,wn) owns a
// 32x32 quadrant as 2x2 16x16x32 f16 fragments (layout validated in R10:
// logits passed). All operands split hi/lo from fp32 during staging.
// ---------------------------------------------------------------------------
__global__ __launch_bounds__(256)
void esn_step_split(const float* __restrict__ X,      // [N,T,V] fp32
                    const float* __restrict__ W_res,  // [B,H,H] fp32
                    const float* __restrict__ W_in,   // [B,H,V] fp32
                    const float* __restrict__ sprev,  // [B,N,H] fp32
                    float* __restrict__ snext,        // [B,N,H] fp32
                    int t, int first)
{
    __shared__ f16 As_hi[64 * LDA];
    __shared__ f16 As_lo[64 * LDA];
    __shared__ f16 Bs_hi[64 * LDA];
    __shared__ f16 Bs_lo[64 * LDA];

    const int id = blockIdx.x;
    const int b  = id >> 6;          // reservoir block 0..5
    const int mt = (id >> 4) & 3;    // batch tile 0..3
    const int it = id & 15;          // unit tile 0..15

    const int tid  = threadIdx.x;
    const int wave = tid >> 6;
    const int lane = tid & 63;
    const int wm   = wave >> 1;
    const int wn   = wave & 1;
    const int l16  = lane & 15;
    const int oct  = lane >> 4;

    // staging map (fp32 sources): thread -> rows srow+16*pp, 4-float col seg
    const int srow = tid >> 4;        // 0..15
    const int sc4  = (tid & 15) << 2; // 0,4,...,60

    floatx4 acc[2][2];   // hi*hi
    floatx4 accl[2][2];  // hi*lo + lo*hi (scaled by 4096)
#pragma unroll
    for (int i = 0; i < 2; ++i)
#pragma unroll
        for (int j = 0; j < 2; ++j) {
            acc[i][j]  = (floatx4)(0.0f);
            accl[i][j] = (floatx4)(0.0f);
        }

    if (!first) {
        const size_t sbase = (size_t)(b * N_TOT + mt * 64) * H_TOT;
        const size_t wbase = (size_t)(b * H_TOT + it * 64) * H_TOT;
        for (int kc = 0; kc < 16; ++kc) {
            const int j0 = kc * 64;
#pragma unroll
            for (int pp = 0; pp < 4; ++pp) {
                const int r = srow + pp * 16;
                U2H4 hi, lo;
                split4(*(const float4*)&sprev[sbase + (size_t)r * H_TOT + j0 + sc4], hi, lo);
                *(uint2*)&As_hi[r * LDA + sc4] = hi.v;
                *(uint2*)&As_lo[r * LDA + sc4] = lo.v;
                split4(*(const float4*)&W_res[wbase + (size_t)r * H_TOT + j0 + sc4], hi, lo);
                *(uint2*)&Bs_hi[r * LDA + sc4] = hi.v;
                *(uint2*)&Bs_lo[r * LDA + sc4] = lo.v;
            }
            __syncthreads();
#pragma unroll
            for (int kk = 0; kk < 64; kk += 32) {
                f16x8 ah[2], al[2], bh[2], bl[2];
#pragma unroll
                for (int x = 0; x < 2; ++x) {
                    const int ar = (wm * 32 + x * 16 + l16) * LDA + kk + oct * 8;
                    const int br = (wn * 32 + x * 16 + l16) * LDA + kk + oct * 8;
                    ah[x] = *(const f16x8*)&As_hi[ar];
                    al[x] = *(const f16x8*)&As_lo[ar];
                    bh[x] = *(const f16x8*)&Bs_hi[br];
                    bl[x] = *(const f16x8*)&Bs_lo[br];
                }
#pragma unroll
                for (int mf = 0; mf < 2; ++mf)
#pragma unroll
                    for (int nf = 0; nf < 2; ++nf) {
                        acc[mf][nf]  = __builtin_amdgcn_mfma_f32_16x16x32_f16(
                            ah[mf], bh[nf], acc[mf][nf], 0, 0, 0);
                        accl[mf][nf] = __builtin_amdgcn_mfma_f32_16x16x32_f16(
                            ah[mf], bl[nf], accl[mf][nf], 0, 0, 0);
                        accl[mf][nf] = __builtin_amdgcn_mfma_f32_16x16x32_f16(
                            al[mf], bh[nf], accl[mf][nf], 0, 0, 0);
                    }
            }
            __syncthreads();
        }
    }

    // ---- input term: += X_t * W_in[b]^T (K = 64), same split scheme ----
    {
#pragma unroll
        for (int pp = 0; pp < 4; ++pp) {
            const int r = srow + pp * 16;
            U2H4 hi, lo;
            split4(*(const float4*)&X[((size_t)(mt * 64 + r) * T_TOT + t) * V_TOT + sc4], hi, lo);
            *(uint2*)&As_hi[r * LDA + sc4] = hi.v;
            *(uint2*)&As_lo[r * LDA + sc4] = lo.v;
            split4(*(const float4*)&W_in[(size_t)(b * H_TOT + it * 64 + r) * V_TOT + sc4], hi, lo);
            *(uint2*)&Bs_hi[r * LDA + sc4] = hi.v;
            *(uint2*)&Bs_lo[r * LDA + sc4] = lo.v;
        }
        __syncthreads();
#pragma unroll
        for (int kk = 0; kk < 64; kk += 32) {
            f16x8 ah[2], al[2], bh[2], bl[2];
#pragma unroll
            for (int x = 0; x < 2; ++x) {
                const int ar = (wm * 32 + x * 16 + l16) * LDA + kk + oct * 8;
                const int br = (wn * 32 + x * 16 + l16) * LDA + kk + oct * 8;
                ah[x] = *(const f16x8*)&As_hi[ar];
                al[x] = *(const f16x8*)&As_lo[ar];
                bh[x] = *(const f16x8*)&Bs_hi[br];
                bl[x] = *(const f16x8*)&Bs_lo[br];
            }
#pragma unroll
            for (int mf = 0; mf < 2; ++mf)
#pragma unroll
                for (int nf = 0; nf < 2; ++nf) {
                    acc[mf][nf]  = __builtin_amdgcn_mfma_f32_16x16x32_f16(
                        ah[mf], bh[nf], acc[mf][nf], 0, 0, 0);
                    accl[mf][nf] = __builtin_amdgcn_mfma_f32_16x16x32_f16(
                        ah[mf], bl[nf], accl[mf][nf], 0, 0, 0);
                    accl[mf][nf] = __builtin_amdgcn_mfma_f32_16x16x32_f16(
                        al[mf], bh[nf], accl[mf][nf], 0, 0, 0);
                }
        }
    }

    // ---- epilogue: combine hi/lo accumulators, tanh, store fp32 state ----
    const int nbase = mt * 64;
    const int hbase = it * 64;
#pragma unroll
    for (int mf = 0; mf < 2; ++mf)
#pragma unroll
        for (int nf = 0; nf < 2; ++nf)
#pragma unroll
            for (int r = 0; r < 4; ++r) {
                const int m  = wm * 32 + mf * 16 + oct * 4 + r; // C/D row (batch n)
                const int nn = wn * 32 + nf * 16 + l16;          // C/D col (unit i)
                const float pre = acc[mf][nf][r] + accl[mf][nf][r] * LO_INV;
                snext[(size_t)(b * N_TOT + nbase + m) * H_TOT + hbase + nn] =
                    tanhf(pre);
            }
}

// ---------------------------------------------------------------------------
// Head (R9 verbatim, pure fp32): logits[t][n][c] = s . W_lin[t][c] + b;
// preds = argmax (first-index ties). One WG per n.
// ---------------------------------------------------------------------------
__global__ __launch_bounds__(256)
void esn_head_fp32(const float* __restrict__ s,      // [B,N,H]
                   const float* __restrict__ W_lin,  // [T,C,F]
                   const float* __restrict__ b_lin,  // [T,C]
                   float* __restrict__ logits,       // [T,N,C]
                   float* __restrict__ preds,        // [T,N]
                   int t)
{
    const int n   = blockIdx.x;
    const int tid = threadIdx.x;

    float acc[4] = {0.f, 0.f, 0.f, 0.f};
    const float* wl = W_lin + (size_t)t * C_TOT * F_TOT;

#pragma unroll
    for (int p = 0; p < 3; ++p) {
        const int f    = p * 2048 + tid * 8;
        const int bblk = f >> 10;
        const int off  = f & 1023;
        const float* sp = &s[(size_t)(bblk * N_TOT + n) * H_TOT + off];
        const float4 f0 = *(const float4*)&sp[0];
        const float4 f1 = *(const float4*)&sp[4];
        const float feat[8] = {f0.x, f0.y, f0.z, f0.w, f1.x, f1.y, f1.z, f1.w};
#pragma unroll
        for (int c = 0; c < 4; ++c) {
            const float4 w0 = *(const float4*)&wl[(size_t)c * F_TOT + f];
            const float4 w1 = *(const float4*)&wl[(size_t)c * F_TOT + f + 4];
            acc[c] += feat[0] * w0.x + feat[1] * w0.y + feat[2] * w0.z +
                      feat[3] * w0.w + feat[4] * w1.x + feat[5] * w1.y +
                      feat[6] * w1.z + feat[7] * w1.w;
        }
    }

#pragma unroll
    for (int off = 32; off > 0; off >>= 1)
#pragma unroll
        for (int c = 0; c < 4; ++c) acc[c] += __shfl_down(acc[c], off);

    __shared__ float red[4][4];
    const int wave = tid >> 6;
    if ((tid & 63) == 0)
#pragma unroll
        for (int c = 0; c < 4; ++c) red[wave][c] = acc[c];
    __syncthreads();
    if (tid == 0) {
        float l[4];
#pragma unroll
        for (int c = 0; c < 4; ++c)
            l[c] = red[0][c] + red[1][c] + red[2][c] + red[3][c] +
                   b_lin[t * C_TOT + c];
        const size_t obase = (size_t)(t * N_TOT + n) * C_TOT;
#pragma unroll
        for (int c = 0; c < 4; ++c) logits[obase + c] = l[c];
        int arg = 0;
        float best = l[0];
#pragma unroll
        for (int c = 1; c < 4; ++c)
            if (l[c] > best) { best = l[c]; arg = c; }
        preds[(size_t)t * N_TOT + n] = (float)arg;
    }
}

extern "C" void kernel_launch(void* const* d_in, const int* in_sizes, int n_in,
                              void* d_out, int out_size, void* d_ws, size_t ws_size,
                              hipStream_t stream) {
    const float* X     = (const float*)d_in[0]; // [256,70,64]
    const float* W_res = (const float*)d_in[1]; // [6,1024,1024]
    const float* W_in  = (const float*)d_in[2]; // [6,1024,64]
    const float* W_lin = (const float*)d_in[3]; // [70,4,6144]
    const float* b_lin = (const float*)d_in[4]; // [70,4]

    float* out    = (float*)d_out;
    float* logits = out;                                  // T*N*C fp32
    float* preds  = out + (size_t)T_TOT * N_TOT * C_TOT;  // T*N   fp32

    // workspace: two fp32 state ping-pong buffers (6.29 MB each, proven-safe)
    const size_t nS = (size_t)B_TOT * N_TOT * H_TOT;
    float* sA = (float*)d_ws;
    float* sB = sA + nS;

    for (int t = 0; t < T_TOT; ++t) {
        const float* prev = (t & 1) ? sB : sA;
        float*       next = (t & 1) ? sA : sB;
        esn_step_split<<<B_TOT * 4 * 16, 256, 0, stream>>>(
            X, W_res, W_in, prev, next, t, t == 0 ? 1 : 0);
        esn_head_fp32<<<N_TOT, 256, 0, stream>>>(
            next, W_lin, b_lin, logits, preds, t);
    }
}

// Round 12
// 2275.787 us; speedup vs baseline: 2.8130x; 1.9378x over previous
//
#include <hip/hip_runtime.h>
#include <stdint.h>

// Echo-state network (fp32 in, fp32 out). Round 12: latency-hiding rebuild of
// the passing split-f16 MFMA engine (R11: 4410 us, absmax 0.0156 = fp32-class).
// R11 counters: MfmaUtil 5%, VALUBusy 15%, HBM 8%, Occ 14% -> latency-bound
// (384 WGs = 1.5 blk/CU; serialized load->barrier->MFMA K-loop).
// Changes:  (1) tile 64x64 -> 64(M)x32(I), grid 384 -> 768 (3 blk/CU);
//           (2) software pipeline: next K-chunk global loads held in registers,
//               issued right after the LDS-store barrier -> global latency
//               overlaps split+ds_read+MFMA of the current chunk.
// Numerics unchanged: operands split in-register to (hi, lo*4096) f16 pairs;
// 3 MFMAs/product; epilogue acc + accl/4096 -> tanh -> fp32 state.
// d_ws: two fp32 state ping-pong buffers, 12.6 MB (proven-safe).

typedef _Float16 f16;
typedef _Float16 f16x8 __attribute__((ext_vector_type(8)));
typedef float floatx4 __attribute__((ext_vector_type(4)));

#define N_TOT 256
#define T_TOT 70
#define V_TOT 64
#define B_TOT 6
#define H_TOT 1024
#define C_TOT 4
#define F_TOT (B_TOT * H_TOT)
#define LDA 72          // f16 LDS row stride (144 B): <=2-way bank aliasing (free)
#define LO_SCALE 4096.0f
#define LO_INV   (1.0f / 4096.0f)

union U2H4 { f16 h[4]; uint2 v; };

static __device__ __forceinline__ void split4(const float4 v, U2H4& hi, U2H4& lo)
{
    const float x[4] = {v.x, v.y, v.z, v.w};
#pragma unroll
    for (int j = 0; j < 4; ++j) {
        const f16 h = (f16)x[j];
        hi.h[j] = h;
        lo.h[j] = (f16)((x[j] - (float)h) * LO_SCALE);
    }
}

// ---------------------------------------------------------------------------
// Step: S_new[b][n][i] = tanh( S W_res[b]^T + X_t W_in[b]^T )
// Tile 64(M=batch) x 32(I=units) per 256-thread WG; grid = 6*4*32 = 768.
// Wave w (0..3) owns M-rows w*16..+15 as 1x2 16x16x32 f16 fragments over I.
// K-loop: BK=64, register-prefetch one chunk ahead.
// ---------------------------------------------------------------------------
__global__ __launch_bounds__(256)
void esn_step_split(const float* __restrict__ X,      // [N,T,V] fp32
                    const float* __restrict__ W_res,  // [B,H,H] fp32
                    const float* __restrict__ W_in,   // [B,H,V] fp32
                    const float* __restrict__ sprev,  // [B,N,H] fp32
                    float* __restrict__ snext,        // [B,N,H] fp32
                    int t, int first)
{
    __shared__ f16 As_hi[64 * LDA];
    __shared__ f16 As_lo[64 * LDA];
    __shared__ f16 Bs_hi[32 * LDA];
    __shared__ f16 Bs_lo[32 * LDA];

    const int id  = blockIdx.x;
    const int b   = id >> 7;         // reservoir block 0..5
    const int rem = id & 127;
    const int mt  = rem >> 5;        // batch tile 0..3  (64 rows)
    const int it  = rem & 31;        // unit tile 0..31  (32 cols)

    const int tid  = threadIdx.x;
    const int wm   = tid >> 6;       // wave 0..3 = M-quadrant
    const int lane = tid & 63;
    const int l16  = lane & 15;
    const int oct  = lane >> 4;

    // staging maps
    const int ra = tid >> 2;          // A row 0..63
    const int ca = (tid & 3) << 4;    // A col {0,16,32,48}; 4 float4 each
    const int rb = tid >> 3;          // B row 0..31
    const int cb = (tid & 7) << 3;    // B col {0,8,...,56}; 2 float4 each

    floatx4 acc[2], accl[2];
#pragma unroll
    for (int j = 0; j < 2; ++j) { acc[j] = (floatx4)(0.0f); accl[j] = (floatx4)(0.0f); }

    if (!first) {
        const float* Aptr = sprev + (size_t)(b * N_TOT + mt * 64 + ra) * H_TOT + ca;
        const float* Bptr = W_res + (size_t)(b * H_TOT + it * 32 + rb) * H_TOT + cb;

        float4 pa[4], pb[2];
#define LOAD_CHUNK(J0)                                    \
        do {                                              \
            pa[0] = *(const float4*)&Aptr[(J0) + 0];      \
            pa[1] = *(const float4*)&Aptr[(J0) + 4];      \
            pa[2] = *(const float4*)&Aptr[(J0) + 8];      \
            pa[3] = *(const float4*)&Aptr[(J0) + 12];     \
            pb[0] = *(const float4*)&Bptr[(J0) + 0];      \
            pb[1] = *(const float4*)&Bptr[(J0) + 4];      \
        } while (0)

        LOAD_CHUNK(0);
        for (int kc = 0; kc < 16; ++kc) {
            if (kc) __syncthreads();   // all waves done reading previous chunk
            // split prefetched registers -> LDS (compiler waits vmcnt here)
            {
                U2H4 hi, lo;
#pragma unroll
                for (int q = 0; q < 4; ++q) {
                    split4(pa[q], hi, lo);
                    *(uint2*)&As_hi[ra * LDA + ca + q * 4] = hi.v;
                    *(uint2*)&As_lo[ra * LDA + ca + q * 4] = lo.v;
                }
#pragma unroll
                for (int q = 0; q < 2; ++q) {
                    split4(pb[q], hi, lo);
                    *(uint2*)&Bs_hi[rb * LDA + cb + q * 4] = hi.v;
                    *(uint2*)&Bs_lo[rb * LDA + cb + q * 4] = lo.v;
                }
            }
            __syncthreads();
            if (kc < 15) LOAD_CHUNK((kc + 1) * 64);  // overlap w/ ds_read+MFMA

#pragma unroll
            for (int kk = 0; kk < 64; kk += 32) {
                const int ar = (wm * 16 + l16) * LDA + kk + oct * 8;
                const f16x8 ah = *(const f16x8*)&As_hi[ar];
                const f16x8 al = *(const f16x8*)&As_lo[ar];
#pragma unroll
                for (int nf = 0; nf < 2; ++nf) {
                    const int br = (nf * 16 + l16) * LDA + kk + oct * 8;
                    const f16x8 bh = *(const f16x8*)&Bs_hi[br];
                    const f16x8 bl = *(const f16x8*)&Bs_lo[br];
                    acc[nf]  = __builtin_amdgcn_mfma_f32_16x16x32_f16(ah, bh, acc[nf], 0, 0, 0);
                    accl[nf] = __builtin_amdgcn_mfma_f32_16x16x32_f16(ah, bl, accl[nf], 0, 0, 0);
                    accl[nf] = __builtin_amdgcn_mfma_f32_16x16x32_f16(al, bh, accl[nf], 0, 0, 0);
                }
            }
        }
#undef LOAD_CHUNK
        __syncthreads();   // chunk-15 reads done before input-term staging
    }

    // ---- input term: += X_t * W_in[b]^T  (K = V = 64) ----
    {
        U2H4 hi, lo;
#pragma unroll
        for (int q = 0; q < 4; ++q) {
            const float4 xv =
                *(const float4*)&X[((size_t)(mt * 64 + ra) * T_TOT + t) * V_TOT + ca + q * 4];
            split4(xv, hi, lo);
            *(uint2*)&As_hi[ra * LDA + ca + q * 4] = hi.v;
            *(uint2*)&As_lo[ra * LDA + ca + q * 4] = lo.v;
        }
#pragma unroll
        for (int q = 0; q < 2; ++q) {
            const float4 wv =
                *(const float4*)&W_in[(size_t)(b * H_TOT + it * 32 + rb) * V_TOT + cb + q * 4];
            split4(wv, hi, lo);
            *(uint2*)&Bs_hi[rb * LDA + cb + q * 4] = hi.v;
            *(uint2*)&Bs_lo[rb * LDA + cb + q * 4] = lo.v;
        }
        __syncthreads();
#pragma unroll
        for (int kk = 0; kk < 64; kk += 32) {
            const int ar = (wm * 16 + l16) * LDA + kk + oct * 8;
            const f16x8 ah = *(const f16x8*)&As_hi[ar];
            const f16x8 al = *(const f16x8*)&As_lo[ar];
#pragma unroll
            for (int nf = 0; nf < 2; ++nf) {
                const int br = (nf * 16 + l16) * LDA + kk + oct * 8;
                const f16x8 bh = *(const f16x8*)&Bs_hi[br];
                const f16x8 bl = *(const f16x8*)&Bs_lo[br];
                acc[nf]  = __builtin_amdgcn_mfma_f32_16x16x32_f16(ah, bh, acc[nf], 0, 0, 0);
                accl[nf] = __builtin_amdgcn_mfma_f32_16x16x32_f16(ah, bl, accl[nf], 0, 0, 0);
                accl[nf] = __builtin_amdgcn_mfma_f32_16x16x32_f16(al, bh, accl[nf], 0, 0, 0);
            }
        }
    }

    // ---- epilogue: combine, tanh, store fp32 state ----
    // C/D map (16x16x32): col = lane&15, row = oct*4 + r.
    const int nbase = mt * 64;
    const int ibase = it * 32;
#pragma unroll
    for (int nf = 0; nf < 2; ++nf)
#pragma unroll
        for (int r = 0; r < 4; ++r) {
            const int m  = wm * 16 + oct * 4 + r;   // batch row within tile
            const int ii = nf * 16 + l16;           // unit col within tile
            const float pre = acc[nf][r] + accl[nf][r] * LO_INV;
            snext[(size_t)(b * N_TOT + nbase + m) * H_TOT + ibase + ii] = tanhf(pre);
        }
}

// ---------------------------------------------------------------------------
// Head (R9 verbatim, pure fp32): logits + argmax preds. One WG per n.
// ---------------------------------------------------------------------------
__global__ __launch_bounds__(256)
void esn_head_fp32(const float* __restrict__ s,      // [B,N,H]
                   const float* __restrict__ W_lin,  // [T,C,F]
                   const float* __restrict__ b_lin,  // [T,C]
                   float* __restrict__ logits,       // [T,N,C]
                   float* __restrict__ preds,        // [T,N]
                   int t)
{
    const int n   = blockIdx.x;
    const int tid = threadIdx.x;

    float acc[4] = {0.f, 0.f, 0.f, 0.f};
    const float* wl = W_lin + (size_t)t * C_TOT * F_TOT;

#pragma unroll
    for (int p = 0; p < 3; ++p) {
        const int f    = p * 2048 + tid * 8;
        const int bblk = f >> 10;
        const int off  = f & 1023;
        const float* sp = &s[(size_t)(bblk * N_TOT + n) * H_TOT + off];
        const float4 f0 = *(const float4*)&sp[0];
        const float4 f1 = *(const float4*)&sp[4];
        const float feat[8] = {f0.x, f0.y, f0.z, f0.w, f1.x, f1.y, f1.z, f1.w};
#pragma unroll
        for (int c = 0; c < 4; ++c) {
            const float4 w0 = *(const float4*)&wl[(size_t)c * F_TOT + f];
            const float4 w1 = *(const float4*)&wl[(size_t)c * F_TOT + f + 4];
            acc[c] += feat[0] * w0.x + feat[1] * w0.y + feat[2] * w0.z +
                      feat[3] * w0.w + feat[4] * w1.x + feat[5] * w1.y +
                      feat[6] * w1.z + feat[7] * w1.w;
        }
    }

#pragma unroll
    for (int off = 32; off > 0; off >>= 1)
#pragma unroll
        for (int c = 0; c < 4; ++c) acc[c] += __shfl_down(acc[c], off);

    __shared__ float red[4][4];
    const int wave = tid >> 6;
    if ((tid & 63) == 0)
#pragma unroll
        for (int c = 0; c < 4; ++c) red[wave][c] = acc[c];
    __syncthreads();
    if (tid == 0) {
        float l[4];
#pragma unroll
        for (int c = 0; c < 4; ++c)
            l[c] = red[0][c] + red[1][c] + red[2][c] + red[3][c] +
                   b_lin[t * C_TOT + c];
        const size_t obase = (size_t)(t * N_TOT + n) * C_TOT;
#pragma unroll
        for (int c = 0; c < 4; ++c) logits[obase + c] = l[c];
        int arg = 0;
        float best = l[0];
#pragma unroll
        for (int c = 1; c < 4; ++c)
            if (l[c] > best) { best = l[c]; arg = c; }
        preds[(size_t)t * N_TOT + n] = (float)arg;
    }
}

extern "C" void kernel_launch(void* const* d_in, const int* in_sizes, int n_in,
                              void* d_out, int out_size, void* d_ws, size_t ws_size,
                              hipStream_t stream) {
    const float* X     = (const float*)d_in[0]; // [256,70,64]
    const float* W_res = (const float*)d_in[1]; // [6,1024,1024]
    const float* W_in  = (const float*)d_in[2]; // [6,1024,64]
    const float* W_lin = (const float*)d_in[3]; // [70,4,6144]
    const float* b_lin = (const float*)d_in[4]; // [70,4]

    float* out    = (float*)d_out;
    float* logits = out;                                  // T*N*C fp32
    float* preds  = out + (size_t)T_TOT * N_TOT * C_TOT;  // T*N   fp32

    const size_t nS = (size_t)B_TOT * N_TOT * H_TOT;
    float* sA = (float*)d_ws;
    float* sB = sA + nS;

    for (int t = 0; t < T_TOT; ++t) {
        const float* prev = (t & 1) ? sB : sA;
        float*       next = (t & 1) ? sA : sB;
        esn_step_split<<<B_TOT * 4 * 32, 256, 0, stream>>>(
            X, W_res, W_in, prev, next, t, t == 0 ? 1 : 0);
        esn_head_fp32<<<N_TOT, 256, 0, stream>>>(
            next, W_lin, b_lin, logits, preds, t);
    }
}